// Round 4
// baseline (68.866 us; speedup 1.0000x reference)
//
#include <hip/hip_runtime.h>

#define B_ 64
#define L_ 512
#define H_ 512
#define CENTER 255

typedef float  f32x4  __attribute__((ext_vector_type(4)));
typedef _Float16 f16x8 __attribute__((ext_vector_type(8)));
typedef unsigned short u16x4 __attribute__((ext_vector_type(4)));
typedef unsigned short USH;

// ws layout (floats):
//   scores   [0,      32768)
//   dec_feat [32768,  65536)
//   cov_feat [65536,  98304)
//   nump     [98304,  229376)  float[256][512]: per-block unnormalized context partials
//   denp     [229376, 229632)  float[256]: per-block softmax partial denominators
//   mp       [229632, 229888)  float[256]: per-block masked score maxima
//   Bpk     [360448, 491520)   ushort[512][512]: fp16(attn_w) bits (row-major n,k)

__device__ __forceinline__ float fast_tanh(float x) {
    float e = __expf(2.0f * x);
    return 1.0f - 2.0f * __builtin_amdgcn_rcpf(e + 1.0f);
}

// ================= pre: cov-direct (0..511) + conv_b (512..639) + dec (640..895) ========
__launch_bounds__(512)
__global__ void pre_kernel(const float* __restrict__ cvg_w, const float* __restrict__ cvg_b,
                           const float* __restrict__ coverage,
                           const float* __restrict__ aw, USH* __restrict__ bh16,
                           const float* __restrict__ hidden, const float* __restrict__ dec_w,
                           const float* __restrict__ dec_b,
                           float* __restrict__ dec_feat, float* __restrict__ cov_feat) {
    __shared__ float pool[34304];      // role A: wl[512] + cs[512][65]; role C: sbuf+pr
    const int bid = blockIdx.x, t = threadIdx.x;
    if (bid < 512) {
        float* wl = pool;                          // [512]
        float* cs = pool + 512;                    // [j][c] = [512][65]
        const int i = bid;
        wl[t] = cvg_w[((size_t)(i * L_ + t)) * H_ + CENTER];   // 1 scattered line/thread
        #pragma unroll 8
        for (int c = 0; c < 64; ++c)
            cs[t * 65 + c] = coverage[c * L_ + t];             // coalesced; write 2/bank
        __syncthreads();
        const int b = t >> 3, jg = t & 7;
        float sum = 0.f;
        #pragma unroll 8
        for (int jj = 0; jj < 64; ++jj) {
            int j = jg * 64 + ((jj + jg * 8) & 63);            // rotation: read 2/bank
            sum += cs[j * 65 + b] * wl[j];
        }
        sum += __shfl_xor(sum, 1, 64);
        sum += __shfl_xor(sum, 2, 64);
        sum += __shfl_xor(sum, 4, 64);
        if (jg == 0) cov_feat[b * L_ + i] = sum + cvg_b[i];
    } else if (bid < 640) {
        int i = (bid - 512) * 512 + t;             // float4 per thread
        float4 x = *(const float4*)&aw[(size_t)i * 4];
        float xs[4] = {x.x, x.y, x.z, x.w};
        u16x4 h;
        #pragma unroll
        for (int j = 0; j < 4; ++j)
            h[j] = __builtin_bit_cast(USH, (_Float16)xs[j]);
        *(u16x4*)&bh16[(size_t)i * 4] = h;
    } else {
        float* sbuf = pool;                        // [512]
        float* pr   = pool + 512;                  // [512]
        const int blk = bid - 640, b = blk >> 2, qq = blk & 3;
        const int ol = t & 127, part = t >> 7;
        sbuf[t] = hidden[b * H_ + t];
        __syncthreads();
        const float* row  = dec_w + (size_t)(qq * 128 + ol) * H_ + part * 128;
        const float* hseg = sbuf + part * 128;
        float d0 = 0.f, d1 = 0.f, d2 = 0.f, d3 = 0.f;
        #pragma unroll
        for (int k = 0; k < 128; k += 16) {
            float4 w0 = *(const float4*)&row[k];
            float4 w1 = *(const float4*)&row[k + 4];
            float4 w2 = *(const float4*)&row[k + 8];
            float4 w3 = *(const float4*)&row[k + 12];
            d0 += w0.x * hseg[k]      + w0.y * hseg[k + 1]  + w0.z * hseg[k + 2]  + w0.w * hseg[k + 3];
            d1 += w1.x * hseg[k + 4]  + w1.y * hseg[k + 5]  + w1.z * hseg[k + 6]  + w1.w * hseg[k + 7];
            d2 += w2.x * hseg[k + 8]  + w2.y * hseg[k + 9]  + w2.z * hseg[k + 10] + w2.w * hseg[k + 11];
            d3 += w3.x * hseg[k + 12] + w3.y * hseg[k + 13] + w3.z * hseg[k + 14] + w3.w * hseg[k + 15];
        }
        pr[t] = d0 + d1 + d2 + d3;
        __syncthreads();
        if (t < 128)
            dec_feat[b * H_ + qq * 128 + t] = pr[t] + pr[t + 128] + pr[t + 256] + pr[t + 384]
                                              + dec_b[qq * 128 + t];
    }
}

// ================= fused MFMA GEMM (fp16) + tanh + dot(v) + split-softmax partials ======
// k-loop byte-identical to the 67.7 us baseline. New tail (NO cross-block sync): block-
// local masked max + exp + denominator over its 128 scores, then unnormalized context
// partial num[h] = sum_l p_l * enc[l][h] over ITS OWN 128 rows (XCD-L2 hot). Partials
// (num/den/m) go to ws; a trivial combine kernel produces exact softmax outputs.
#define BM 128

#define STAGE_B(BUF, KS1)                                                                  \
    {                                                                                      \
        _Pragma("unroll")                                                                  \
        for (int it = 0; it < 2; ++it)                                                     \
            __builtin_amdgcn_global_load_lds(                                              \
                (const __attribute__((address_space(1))) void*)(bh16 + goffB[it] + (KS1) * 32), \
                (__attribute__((address_space(3))) void*)&Bsh[BUF][(wv * 2 + it) * 512],   \
                16, 0, 0);                                                                 \
    }

#define CVTWRITEA(BUF, A4)                                                                 \
    {                                                                                      \
        float axs[4] = {A4.x, A4.y, A4.z, A4.w};                                           \
        u16x4 hh;                                                                          \
        _Pragma("unroll")                                                                  \
        for (int j = 0; j < 4; ++j)                                                        \
            hh[j] = __builtin_bit_cast(USH, (_Float16)axs[j]);                             \
        *(u16x4*)&Ash[BUF][awoff] = hh;                                                    \
    }

__launch_bounds__(1024, 4)
__global__ void fused_score_mfma(const float* __restrict__ enc,
                                 const USH* __restrict__ bh16,
                                 const float* __restrict__ attn_b,
                                 const float* __restrict__ dec_feat,
                                 const float* __restrict__ cov_feat,
                                 const float* __restrict__ v,
                                 const int* __restrict__ mask,
                                 float* __restrict__ scores,
                                 float* __restrict__ nump,
                                 float* __restrict__ denp,
                                 float* __restrict__ mp) {
    __shared__ USH Bsh[3][16384];      // [buf][512n x 32k swizzled fp16] = 96 KB
    __shared__ USH Ash[2][4096];       // [buf][128r x 32k swizzled fp16] = 16 KB

    const int t  = threadIdx.x;
    const int wv = t >> 6, ln = t & 63;
    const int wr = wv >> 3, wc = wv & 7;     // 2M x 8N, wave tile 64 x 64
    const int q  = ln >> 4, cl = ln & 15;
    const int m0 = blockIdx.x * BM;
    const int b  = blockIdx.x >> 2;          // 4 row-tiles per batch row
    const int lt = blockIdx.x & 3;

    int goffB[2];
    #pragma unroll
    for (int it = 0; it < 2; ++it) {
        int c   = wv * 2 + it;
        int srl = ln >> 3;
        int u   = (ln & 7) ^ (srl & 7);
        int n   = c * 16 + srl * 2 + (u >> 2);
        goffB[it] = n * 512 + (u & 3) * 8;
    }
    const int sA   = (((cl & 1) * 4 + q) ^ ((cl >> 1) & 7)) * 8;
    const int aoff = wr * 2048 + (cl >> 1) * 64 + sA;
    const int boff = wc * 2048 + (cl >> 1) * 64 + sA;

    const int arow = t >> 3, akoct = t & 7;
    const int asw  = ((arow & 1) * 4 + (akoct >> 1)) ^ ((arow >> 1) & 7);
    const int awoff = (arow >> 1) * 64 + asw * 8 + (akoct & 1) * 4;
    const float* agsrc = enc + (size_t)(m0 + arow) * H_ + akoct * 4;

    f32x4 acc[4][4];
    #pragma unroll
    for (int mf = 0; mf < 4; ++mf)
        #pragma unroll
        for (int nf = 0; nf < 4; ++nf) acc[mf][nf] = (f32x4){0.f, 0.f, 0.f, 0.f};

    float4 aP = *(const float4*)(agsrc + 32);
    float4 c0 = *(const float4*)agsrc;
    __builtin_amdgcn_sched_barrier(0);
    STAGE_B(0, 0);
    STAGE_B(1, 1);
    __builtin_amdgcn_sched_barrier(0);
    CVTWRITEA(0, c0);
    asm volatile("s_waitcnt lgkmcnt(0)" ::: "memory");
    asm volatile("s_waitcnt vmcnt(2)" ::: "memory");
    __builtin_amdgcn_sched_barrier(0);
    __builtin_amdgcn_s_barrier();

    #pragma unroll
    for (int ks = 0; ks < 16; ++ks) {
        const int curB = ks % 3;
        const int curA = ks & 1, nxtA = curA ^ 1;
        float4 aN;
        if (ks < 14) {
            STAGE_B((ks + 2) % 3, ks + 2);
            aN = *(const float4*)(agsrc + (ks + 2) * 32);
            __builtin_amdgcn_sched_barrier(0);
        }

        f16x8 ah[4];
        #pragma unroll
        for (int mf = 0; mf < 4; ++mf)
            ah[mf] = *(const f16x8*)&Ash[curA][aoff + mf * 512];
        __builtin_amdgcn_s_setprio(1);
        #pragma unroll
        for (int nf = 0; nf < 4; ++nf) {
            f16x8 bh = *(const f16x8*)&Bsh[curB][boff + nf * 512];
            #pragma unroll
            for (int mf = 0; mf < 4; ++mf)
                acc[mf][nf] = __builtin_amdgcn_mfma_f32_16x16x32_f16(ah[mf], bh, acc[mf][nf], 0, 0, 0);
        }
        __builtin_amdgcn_s_setprio(0);

        if (ks < 15) {
            CVTWRITEA(nxtA, aP);
            aP = aN;
            asm volatile("s_waitcnt lgkmcnt(0)" ::: "memory");
            if (ks < 14)
                asm volatile("s_waitcnt vmcnt(3)" ::: "memory");
            else
                asm volatile("s_waitcnt vmcnt(0)" ::: "memory");
            __builtin_amdgcn_sched_barrier(0);
            __builtin_amdgcn_s_barrier();
        }
    }
    __syncthreads();

    float (*scred)[BM] = (float (*)[BM])Ash;
    float addv[4], vvv[4];
    #pragma unroll
    for (int nf = 0; nf < 4; ++nf) {
        int n = wc * 64 + nf * 16 + cl;
        addv[nf] = attn_b[n] + dec_feat[b * H_ + n];
        vvv[nf]  = v[b * H_ + n];
    }
    #pragma unroll
    for (int mf = 0; mf < 4; ++mf) {
        #pragma unroll
        for (int reg = 0; reg < 4; ++reg) {
            int row = wr * 64 + mf * 16 + q * 4 + reg;
            float cf = cov_feat[m0 + row];
            float s = 0.f;
            #pragma unroll
            for (int nf = 0; nf < 4; ++nf)
                s += fast_tanh(acc[mf][nf][reg] + addv[nf] + cf) * vvv[nf];
            s += __shfl_xor(s, 1, 64);
            s += __shfl_xor(s, 2, 64);
            s += __shfl_xor(s, 4, 64);
            s += __shfl_xor(s, 8, 64);
            if (cl == 0) scred[wc][row] = s;
        }
    }
    __syncthreads();

    float* sloc = (float*)&Bsh[0][0];      // [128] block scores   (Bsh free after k-loop)
    float* pv   = sloc + 128;              // [128] exp(s - m_blk), 0 for masked
    float* rbuf = sloc + 256;              // [8] reduction scratch
    bool mk = false;
    if (t < BM) {
        float s = 0.f;
        #pragma unroll
        for (int g = 0; g < 8; ++g) s += scred[g][t];
        scores[m0 + t] = s;
        sloc[t] = s;
        mk = (mask[b * L_ + lt * BM + t] == 1);
    }
    // ---- block-local masked max over the 128 scores (threads 0..127 = waves 0,1) ----
    float mval = (t < BM && mk) ? sloc[t] : -INFINITY;
    #pragma unroll
    for (int d = 1; d <= 32; d <<= 1) mval = fmaxf(mval, __shfl_xor(mval, d, 64));
    if (t < BM && (t & 63) == 0) rbuf[t >> 6] = mval;
    __syncthreads();
    const float mb = fmaxf(rbuf[0], rbuf[1]);
    // ---- exp + local denominator ----
    float pval = 0.f;
    if (t < BM) {
        pval = mk ? __expf(sloc[t] - mb) : 0.f;
        pv[t] = pval;
    }
    float dsum = pval;
    #pragma unroll
    for (int d = 1; d <= 32; d <<= 1) dsum += __shfl_xor(dsum, d, 64);
    if (t < BM && (t & 63) == 0) rbuf[4 + (t >> 6)] = dsum;
    __syncthreads();
    if (t == 0) {
        denp[blockIdx.x] = rbuf[4] + rbuf[5];
        mp[blockIdx.x]   = mb;
    }
    // ---- unnormalized context partial over this block's 128 enc rows (L2-hot) ----
    {
        const int c4 = t & 127, rg = t >> 7;   // 128 float4 cols x 8 row-groups
        const float4* ebase = (const float4*)enc + ((size_t)(m0 + rg)) * 128 + c4;
        float4 a4 = {0.f, 0.f, 0.f, 0.f};
        #pragma unroll
        for (int k = 0; k < 16; ++k) {         // rows rg, rg+8, ..., rg+120
            float wl_ = pv[rg + 8 * k];
            float4 e = ebase[(size_t)(8 * k) * 128];
            a4.x += wl_ * e.x; a4.y += wl_ * e.y; a4.z += wl_ * e.z; a4.w += wl_ * e.w;
        }
        __syncthreads();                       // scred (Ash) dead; reuse for reduce
        ((float4*)Ash)[rg * 128 + c4] = a4;    // 8 x 128 float4 = 16 KB = Ash exactly
        __syncthreads();
        if (t < 512) {
            const float* Ar = (const float*)Ash;
            float csum = 0.f;
            #pragma unroll
            for (int g = 0; g < 8; ++g) csum += Ar[g * 512 + t];
            nump[blockIdx.x * 512 + t] = csum;
        }
    }
}

// ================= finish: combine 4 split-softmax partials per batch ===================
// ctx = (sum_i e^{m_i-M} num_i[h]) / dentot;  w_l = exp(s_l-M)/dentot (exact softmax).
__launch_bounds__(512)
__global__ void finish_kernel(const float* __restrict__ scores, const int* __restrict__ mask,
                              const float* __restrict__ coverage,
                              const float* __restrict__ nump, const float* __restrict__ denp,
                              const float* __restrict__ mp, float* __restrict__ out) {
    const int b = blockIdx.x, t = threadIdx.x;
    float m0 = mp[b * 4 + 0], m1 = mp[b * 4 + 1], m2 = mp[b * 4 + 2], m3 = mp[b * 4 + 3];
    float M = fmaxf(fmaxf(m0, m1), fmaxf(m2, m3));
    float d0 = denp[b * 4 + 0], d1 = denp[b * 4 + 1], d2 = denp[b * 4 + 2], d3 = denp[b * 4 + 3];
    float f0 = d0 > 0.f ? __expf(m0 - M) : 0.f;
    float f1 = d1 > 0.f ? __expf(m1 - M) : 0.f;
    float f2 = d2 > 0.f ? __expf(m2 - M) : 0.f;
    float f3 = d3 > 0.f ? __expf(m3 - M) : 0.f;
    float inv = 1.0f / (f0 * d0 + f1 * d1 + f2 * d2 + f3 * d3);
    const int idx = b * L_ + t;
    bool mk = (mask[idx] == 1);
    float sv = scores[idx];
    float wt = mk ? __expf(sv - M) * inv : 0.f;
    out[B_ * H_ + idx] = wt;                                   // attn_weights
    out[B_ * H_ + B_ * L_ + idx] = coverage[idx] + wt;         // new_coverage
    float ctx = (f0 * nump[(b * 4 + 0) * 512 + t] + f1 * nump[(b * 4 + 1) * 512 + t]
               + f2 * nump[(b * 4 + 2) * 512 + t] + f3 * nump[(b * 4 + 3) * 512 + t]) * inv;
    out[b * H_ + t] = ctx;                                     // context_vector
}

extern "C" void kernel_launch(void* const* d_in, const int* in_sizes, int n_in,
                              void* d_out, int out_size, void* d_ws, size_t ws_size,
                              hipStream_t stream) {
    const float* enc      = (const float*)d_in[0];
    const int*   mask     = (const int*)d_in[1];
    const float* hidden   = (const float*)d_in[2];
    const float* coverage = (const float*)d_in[3];
    const float* attn_w   = (const float*)d_in[4];
    const float* attn_b   = (const float*)d_in[5];
    const float* dec_w    = (const float*)d_in[6];
    const float* dec_b    = (const float*)d_in[7];
    const float* cvg_w    = (const float*)d_in[8];
    const float* cvg_b    = (const float*)d_in[9];
    const float* v        = (const float*)d_in[10];
    float* out = (float*)d_out;
    float* ws  = (float*)d_ws;
    float* scores   = ws;
    float* dec_feat = ws + 32768;
    float* cov_feat = ws + 65536;
    float* nump     = ws + 98304;
    float* denp     = ws + 229376;
    float* mp       = ws + 229632;
    USH* bpk = (USH*)(ws + 360448);

    hipLaunchKernelGGL(pre_kernel,       dim3(896),  dim3(512),  0, stream,
                       cvg_w, cvg_b, coverage, attn_w, bpk, hidden, dec_w, dec_b,
                       dec_feat, cov_feat);
    hipLaunchKernelGGL(fused_score_mfma, dim3(256),  dim3(1024), 0, stream,
                       enc, bpk, attn_b, dec_feat, cov_feat, v, mask,
                       scores, nump, denp, mp);
    hipLaunchKernelGGL(finish_kernel,    dim3(64),   dim3(512),  0, stream,
                       scores, mask, coverage, nump, denp, mp, out);
}